// Round 21
// baseline (345.712 us; speedup 1.0000x reference)
//
#include <hip/hip_runtime.h>
#include <hip/hip_bf16.h>
#include <hip/hip_fp8.h>

// Problem constants
#define NB 256
#define TT 64
#define DD 1280
#define WW 256
#define HH 512
#define VV 10000
#define VP 10112           // vocab padded to 79*128
#define NCT 79             // number of 128-col vocab tiles
#define MROWS (NB*TT)      // 16384 score rows

typedef short short8 __attribute__((ext_vector_type(8)));
typedef float f32x4 __attribute__((ext_vector_type(4)));
typedef int   int4v __attribute__((ext_vector_type(4)));
typedef int   int8v __attribute__((ext_vector_type(8)));

static __device__ __forceinline__ unsigned short f2bf(float x){
    unsigned int u = __float_as_uint(x);
    unsigned int r = u + 0x7FFFu + ((u >> 16) & 1u);   // RNE
    return (unsigned short)(r >> 16);
}
static __device__ __forceinline__ float bf2f(unsigned short u){
    return __uint_as_float(((unsigned int)u) << 16);
}
static __device__ __forceinline__ unsigned char f2f8(float x){
    __hip_fp8_e4m3 q(x);                                // OCP e4m3fn
    return (unsigned char)q.__x;
}
static __device__ __forceinline__ float f82f(unsigned char b){
    __hip_fp8_e4m3 q; q.__x = b;
    return (float)q;
}
// fp4 e2m1 encode of x (round to nearest on the grid {0,.5,1,1.5,2,3,4,6})
static __device__ __forceinline__ unsigned enc4(float x){
    unsigned s = (x < 0.f) ? 8u : 0u;
    float a = fabsf(x);
    unsigned m;
    if      (a < 0.25f) m = 0;
    else if (a < 0.75f) m = 1;
    else if (a < 1.25f) m = 2;
    else if (a < 1.75f) m = 3;
    else if (a < 2.5f)  m = 4;
    else if (a < 3.5f)  m = 5;
    else if (a < 5.0f)  m = 6;
    else                m = 7;
    return s | m;
}
static __device__ __forceinline__ void gload16b(const unsigned char* g, unsigned char* l){
    __builtin_amdgcn_global_load_lds(
        (const __attribute__((address_space(1))) void*)g,
        (__attribute__((address_space(3))) void*)l, 16, 0, 0);
}

// K-tiled fp8 operand layout for the scores GEMM:
//   addr(row, k) = ((row>>7)*4 + (k>>7))*16384 + (row&127)*128 + (k&127)

// ---------- FUSED PREP: h0 | transpose_bf(Wx) | wh4 | transpose_f8(W_out) | biaspad ----------
// Sections by blockIdx.x: [0,256) h0 | [256,384) tbf | [384,896) wh4
//                         [896,5952) tf8 | [5952,5992) biaspad
__global__ __launch_bounds__(256) void k_prep(const float* __restrict__ feat,
                                              const float* __restrict__ W_proj,
                                              const float* __restrict__ bp,
                                              float* __restrict__ h0,
                                              const float* __restrict__ Wx,
                                              unsigned short* __restrict__ WxT,
                                              const float* __restrict__ Wh,
                                              unsigned char* __restrict__ WhT4,
                                              const float* __restrict__ W_out,
                                              unsigned char* __restrict__ WoT8p,
                                              const float* __restrict__ bo,
                                              float* __restrict__ bop){
    __shared__ unsigned short tileS[64][17];            // 2176 B
    __shared__ float fs[DD];                            // 5120 B (h0 section)
    int b = blockIdx.x;
    int tid = threadIdx.x;
    if (b < 256){
        // --- h0: one sample per block; thread covers cols tid and tid+256 (f32) ---
        int n = b;
        for (int i = tid; i < DD; i += 256) fs[i] = feat[(size_t)n*DD + i];
        __syncthreads();
        int c0 = tid, c1 = tid + 256;
        float a0 = 0.f, a1 = 0.f;
        for (int d = 0; d < DD; ++d){
            float fv = fs[d];
            a0 += fv * W_proj[(size_t)d*HH + c0];
            a1 += fv * W_proj[(size_t)d*HH + c1];
        }
        h0[(size_t)n*HH + c0] = a0 + bp[c0];
        h0[(size_t)n*HH + c1] = a1 + bp[c1];
    } else if (b < 384){
        // --- transpose_bf: Wx[256][512] -> WxT[512][256] bf16 ---
        int r = b - 256;                                // 8 x 16
        int c0 = (r & 7)*64, r0 = (r >> 3)*16;
        int c = tid & 63, rr = tid >> 6;
        #pragma unroll
        for (int j = 0; j < 4; ++j){
            int rw_ = rr + j*4;
            tileS[c][rw_] = f2bf(Wx[(size_t)(r0+rw_)*HH + c0 + c]);
        }
        __syncthreads();
        int rw = tid & 15, cw = tid >> 4;
        #pragma unroll
        for (int j = 0; j < 4; ++j){
            int c2 = cw + j*16;
            WxT[(size_t)(c0+c2)*WW + r0 + rw] = tileS[c2][rw];
        }
    } else if (b < 896){
        // --- wh4 ---
        int r = b - 384;                                // 512 blocks
        int j = r >> 1;                                 // k-pair 0..255
        int col = (r & 1)*256 + tid;
        float w0 = Wh[(size_t)(2*j  )*HH + col] * 32.0f;
        float w1 = Wh[(size_t)(2*j+1)*HH + col] * 32.0f;
        WhT4[(size_t)col*256 + j] = (unsigned char)(enc4(w0) | (enc4(w1) << 4));
    } else if (b < 5952){
        // --- transpose_f8: W_out[512][10000] -> K-tiled fp8 (pad cols to VP) ---
        unsigned char (*tileC)[20] = reinterpret_cast<unsigned char (*)[20]>(&tileS[0][0]);
        int r = b - 896;                                // 158 x 32
        int c0 = (r % 158)*64, r0 = (r / 158)*16;
        int c = tid & 63, rr = tid >> 6;
        #pragma unroll
        for (int j = 0; j < 4; ++j){
            int rw_ = rr + j*4;
            unsigned char v = 0;
            if (c0 + c < VV) v = f2f8(W_out[(size_t)(r0+rw_)*VV + c0 + c]);
            tileC[c][rw_] = v;
        }
        __syncthreads();
        int rw = tid & 15, cw = tid >> 4;
        #pragma unroll
        for (int j = 0; j < 4; ++j){
            int c2 = cw + j*16;
            int col = c0 + c2, k = r0 + rw;
            if (col < VP){
                size_t addr = ((size_t)((col >> 7)*4 + (k >> 7)))*16384
                            + (unsigned)((col & 127)*128 + (k & 127));
                WoT8p[addr] = tileC[c2][rw];
            }
        }
    } else {
        int i = (b - 5952)*256 + tid;
        // bias pre-scaled by log2(e) so the GEMM epilogue is one fma + one exp2
        if (i < VP) bop[i] = (i < VV) ? bo[i]*1.44269504f : -30000.0f;
    }
}

// ---------- E2[v][h] = sum_w W_embed[v][w] * Wx[w][h] + b[h]  (bf16 MFMA, bf16 out) ----------
// grid (157, 4): 8 cts per block for 4x latency-hiding parallelism.
__global__ __launch_bounds__(256) void k_e2(const float* __restrict__ We,
                                            const unsigned short* __restrict__ WxT,
                                            const float* __restrict__ bias,
                                            unsigned short* __restrict__ E2b){
    int lane = threadIdx.x & 63;
    int wv   = threadIdx.x >> 6;           // 0..3
    int l15 = lane & 15, lhi = lane >> 4;
    int rbase = blockIdx.x*64 + wv*16;
    int arow = rbase + l15; if (arow > VV-1) arow = VV-1;
    short8 a[8];
    #pragma unroll
    for (int kk = 0; kk < 8; ++kk){
        const float* src = We + (size_t)arow*WW + kk*32 + lhi*8;
        float4 g0 = *reinterpret_cast<const float4*>(src);
        float4 g1 = *reinterpret_cast<const float4*>(src + 4);
        short8 v;
        v[0]=(short)f2bf(g0.x); v[1]=(short)f2bf(g0.y); v[2]=(short)f2bf(g0.z); v[3]=(short)f2bf(g0.w);
        v[4]=(short)f2bf(g1.x); v[5]=(short)f2bf(g1.y); v[6]=(short)f2bf(g1.z); v[7]=(short)f2bf(g1.w);
        a[kk] = v;
    }
    int ct0 = blockIdx.y*8;
    for (int ct = ct0; ct < ct0+8; ++ct){
        int c0 = ct*16;
        f32x4 acc = {0.f,0.f,0.f,0.f};
        #pragma unroll
        for (int kk = 0; kk < 8; ++kk){
            short8 b = *reinterpret_cast<const short8*>(WxT + (size_t)(c0 + l15)*WW + kk*32 + lhi*8);
            acc = __builtin_amdgcn_mfma_f32_16x16x32_bf16(a[kk], b, acc, 0, 0, 0);
        }
        float bb = bias[c0 + l15];
        #pragma unroll
        for (int r = 0; r < 4; ++r){
            int row = rbase + lhi*4 + r;
            if (row < VV) E2b[(size_t)row*HH + c0 + l15] = f2bf(acc[r] + bb);
        }
    }
}

// ---------- RNN v4: 1 sample/block (256 blocks = 1/CU), 8 waves x 64 cols.
//             16 independent single-MFMA accumulators per step. ----------
__global__ __launch_bounds__(512) void k_rnn(const float* __restrict__ h0,
                                             const unsigned char* __restrict__ WhT4,
                                             const unsigned short* __restrict__ E2b,
                                             const int* __restrict__ caps,
                                             unsigned char* __restrict__ hA8){
    __shared__ __align__(32) unsigned char hl[2][HH];   // fp8 h, double-buffered (1 KB)
    int tid = threadIdx.x;
    int lane = tid & 63, wv = tid >> 6;      // 8 waves
    int l15 = lane & 15, lhi = lane >> 4;
    int n = blockIdx.x;
    int c0w = wv*64;                         // 64 cols per wave
    int mycol = c0w + lane;                  // col this lane finishes (ct==lhi)
    unsigned char* hbase = hA8 + ((size_t)((n>>1)*4 + (wv>>1)))*16384
                               + (unsigned)((n&1)*64*128 + (mycol & 127));

    int4v b[4][4];
    #pragma unroll
    for (int ct = 0; ct < 4; ++ct){
        int col = c0w + ct*16 + l15;
        #pragma unroll
        for (int kt = 0; kt < 4; ++kt){
            b[ct][kt] = *reinterpret_cast<const int4v*>(WhT4 + (size_t)col*256 + kt*64 + lhi*16);
            asm volatile("" : "+v"(b[ct][kt]));   // opaque: no remat / re-stream
        }
    }
    hl[0][tid] = f2f8(h0[(size_t)n*HH + tid]);
    __syncthreads();
    int cur = 0;
    const f32x4 z = {0.f,0.f,0.f,0.f};
    for (int t = 0; t < TT; ++t){
        int tok = caps[n*(TT+1) + t];
        unsigned short xv = E2b[(size_t)tok*HH + mycol];
        int8v a[4];
        #pragma unroll
        for (int kt = 0; kt < 4; ++kt)
            a[kt] = *reinterpret_cast<const int8v*>(&hl[cur][kt*128 + lhi*32]);
        f32x4 acc[4][4];
        #pragma unroll
        for (int ct = 0; ct < 4; ++ct)
            #pragma unroll
            for (int kt = 0; kt < 4; ++kt){
                int8v bb = __builtin_shufflevector(b[ct][kt], b[ct][kt], 0,1,2,3,0,1,2,3);
                acc[ct][kt] = __builtin_amdgcn_mfma_scale_f32_16x16x128_f8f6f4(
                    a[kt], bb, z,
                    0, 4,                        // cbsz=fp8(A), blgp=fp4(B)
                    0, (int)0x7F7F7F7F,          // A scale 2^0
                    0, (int)0x7A7A7A7A);         // B scale 2^-5
            }
        float s0 = (acc[0][0][0] + acc[0][1][0]) + (acc[0][2][0] + acc[0][3][0]);
        float s1 = (acc[1][0][0] + acc[1][1][0]) + (acc[1][2][0] + acc[1][3][0]);
        float s2 = (acc[2][0][0] + acc[2][1][0]) + (acc[2][2][0] + acc[2][3][0]);
        float s3 = (acc[3][0][0] + acc[3][1][0]) + (acc[3][2][0] + acc[3][3][0]);
        float v = (lhi == 0) ? s0 : (lhi == 1) ? s1 : (lhi == 2) ? s2 : s3;
        float x = v + bf2f(xv);
        float e = __expf(2.f*x);
        float th = 1.f - 2.f/(e + 1.f);          // tanh(x), saturates correctly
        unsigned char hv = f2f8(th);
        hl[cur^1][mycol] = hv;
        hbase[t*128] = hv;                       // K-tiled store, coalesced per wave
        __syncthreads();
        cur ^= 1;
    }
}

// ---------- scores: MX-fp8 GEMM, FULL-K single-stage (128 KB LDS, ONE barrier) ----------
// Stage all 4 kt-blocks of A and B once (16 gload_lds/thread), one vmcnt-draining
// __syncthreads, then the full K sweep with ZERO intervening barriers (LDS is
// read-only after the stage). Deletes 6 of 8 per-block barriers + all mid-loop
// vmcnt drains — the measured ~5 us/block stall term. 1 block/CU (128 KB LDS).
__global__ __launch_bounds__(512) void k_scores(const unsigned char* __restrict__ hA8,
                                                const unsigned char* __restrict__ WoT8p,
                                                const float* __restrict__ bop,
                                                float* __restrict__ pps){  // [NCT][MROWS]
    __shared__ unsigned char As[4*16384];   // 64 KB: full K for the 128-row panel
    __shared__ unsigned char Bs[4*16384];   // 64 KB
    int bid = blockIdx.x;
    int x = bid & 7;                 // XCD (blocks round-robin across XCDs)
    int local = bid >> 3;            // 0..1263
    int ct = local >> 4;             // ct-major within XCD
    int rt = x*16 + (local & 15);    // rt-minor: 16 consecutive row-tiles per XCD

    int tid = threadIdx.x;
    int lane = tid & 63, wv = tid >> 6;      // 8 waves
    int l15 = lane & 15, lhi = lane >> 4;
    int wr = wv >> 1, wc = wv & 1;           // 4 x 2 wave grid: 32 rows x 64 cols each
    const unsigned char* Abase = hA8   + (size_t)rt*65536;   // panel rt, 4 kt blocks
    const unsigned char* Bbase = WoT8p + (size_t)ct*65536;   // panel ct, 4 kt blocks

    // stage everything: 4096 chunks per matrix, 8 per thread each
    #pragma unroll
    for (int i = 0; i < 8; ++i){
        unsigned chunk = (unsigned)(i*512 + tid);            // 0..4095
        unsigned rowloc = (chunk & 1023u) >> 3;
        unsigned off = (chunk >> 10)*16384u + rowloc*128u
                     + (((chunk & 7u) ^ (rowloc & 7u))*16u);
        gload16b(Abase + off, As + chunk*16u);
        gload16b(Bbase + off, Bs + chunk*16u);
    }
    __syncthreads();   // drains all 16 gloads (vmcnt 0); LDS read-only hereafter

    f32x4 acc[2][4];
    #pragma unroll
    for (int m = 0; m < 2; ++m)
        #pragma unroll
        for (int n = 0; n < 4; ++n)
            acc[m][n] = (f32x4){0.f,0.f,0.f,0.f};

    #pragma unroll
    for (int kt = 0; kt < 4; ++kt){
        const unsigned char* Ak = As + kt*16384;
        const unsigned char* Bk = Bs + kt*16384;
        int8v af[2];
        #pragma unroll
        for (int m = 0; m < 2; ++m){
            unsigned row = (unsigned)(wr*32 + m*16 + l15);
            int4v c0 = *reinterpret_cast<const int4v*>(Ak + row*128 + (((unsigned)(lhi*2+0) ^ (row&7))*16));
            int4v c1 = *reinterpret_cast<const int4v*>(Ak + row*128 + (((unsigned)(lhi*2+1) ^ (row&7))*16));
            af[m] = __builtin_shufflevector(c0, c1, 0,1,2,3,4,5,6,7);
        }
        #pragma unroll
        for (int n = 0; n < 4; ++n){
            unsigned col = (unsigned)(wc*64 + n*16 + l15);
            int4v c0 = *reinterpret_cast<const int4v*>(Bk + col*128 + (((unsigned)(lhi*2+0) ^ (col&7))*16));
            int4v c1 = *reinterpret_cast<const int4v*>(Bk + col*128 + (((unsigned)(lhi*2+1) ^ (col&7))*16));
            int8v bf = __builtin_shufflevector(c0, c1, 0,1,2,3,4,5,6,7);
            #pragma unroll
            for (int m = 0; m < 2; ++m)
                acc[m][n] = __builtin_amdgcn_mfma_scale_f32_16x16x128_f8f6f4(
                    af[m], bf, acc[m][n],
                    0, 0,
                    0, (int)0x7F7F7F7F,
                    0, (int)0x7F7F7F7F);
        }
    }

    const float LOG2E = 1.44269504f;
    float srun[2][4];
    #pragma unroll
    for (int m = 0; m < 2; ++m)
        #pragma unroll
        for (int r = 0; r < 4; ++r) srun[m][r] = 0.f;
    #pragma unroll
    for (int n = 0; n < 4; ++n){
        int colg = ct*128 + wc*64 + n*16 + l15;
        float bb2 = bop[colg];                         // already * log2e (or -30000)
        #pragma unroll
        for (int m = 0; m < 2; ++m)
            #pragma unroll
            for (int r = 0; r < 4; ++r)
                srun[m][r] += exp2f(fmaf(acc[m][n][r], LOG2E, bb2));
    }
    #pragma unroll
    for (int off = 1; off < 16; off <<= 1)
        #pragma unroll
        for (int m = 0; m < 2; ++m)
            #pragma unroll
            for (int r = 0; r < 4; ++r)
                srun[m][r] += __shfl_xor(srun[m][r], off, 64);
    // cross-wc reduction: waves (wr,0) and (wr,1) hold partials for the SAME rows.
    __syncthreads();           // REQUIRED: all waves' K-sweep LDS reads drained
    float* red = (float*)As;   // 128 floats scratch
    if (wc == 1 && l15 == 0){
        #pragma unroll
        for (int m = 0; m < 2; ++m)
            #pragma unroll
            for (int r = 0; r < 4; ++r){
                int ri = wr*32 + m*16 + lhi*4 + r;      // 0..127
                red[ri] = srun[m][r];
            }
    }
    __syncthreads();
    if (wc == 0 && l15 == 0){
        #pragma unroll
        for (int m = 0; m < 2; ++m)
            #pragma unroll
            for (int r = 0; r < 4; ++r){
                int ri = wr*32 + m*16 + lhi*4 + r;
                int gr = rt*128 + ri;
                pps[(size_t)ct*MROWS + gr] = srun[m][r] + red[ri];
            }
    }
}

// ---------- t0[row] = h8[row,:] . Wo8[:, tgt] + b_out[tgt]  (one wave per row) ----------
__global__ __launch_bounds__(256) void k_tsc(const unsigned char* __restrict__ hA8,
                                             const unsigned char* __restrict__ WoT8p,
                                             const float* __restrict__ bo,
                                             const int* __restrict__ caps,
                                             float* __restrict__ t0arr){
    int lane = threadIdx.x & 63, w = threadIdx.x >> 6;   // 4 waves
    int row = blockIdx.x*4 + w;                          // 4096 blocks
    int tgt = caps[(row >> 6)*(TT+1) + (row & 63) + 1];
    int k0 = lane*8;
    int ktile = k0 >> 7, kin = k0 & 127;
    const unsigned char* hp = hA8   + ((size_t)((row >> 7)*4 + ktile))*16384
                                    + (unsigned)((row & 127)*128 + kin);
    const unsigned char* wp = WoT8p + ((size_t)((tgt >> 7)*4 + ktile))*16384
                                    + (unsigned)((tgt & 127)*128 + kin);
    float sum = 0.f;
    #pragma unroll
    for (int j = 0; j < 8; ++j)
        sum += f82f(hp[j]) * f82f(wp[j]);
    #pragma unroll
    for (int off = 1; off < 64; off <<= 1)
        sum += __shfl_xor(sum, off, 64);
    if (lane == 0) t0arr[row] = sum + bo[tgt];
}

// ---------- loss stage 1: per-row nll, 256 blocks x 64 rows, 4-way ct-split ----------
__global__ __launch_bounds__(256) void k_loss1(const float* __restrict__ pps,
                                               const float* __restrict__ t0arr,
                                               const int* __restrict__ caps,
                                               float* __restrict__ bsum){
    __shared__ float reds[256];
    int tid = threadIdx.x;
    int rloc = tid & 63, q = tid >> 6;      // q = 0..3: ct quarter
    int row = blockIdx.x*64 + rloc;
    int c0 = q*20, c1 = (q == 3) ? NCT : c0 + 20;
    float s = 0.f;
    for (int ct = c0; ct < c1; ++ct)
        s += pps[(size_t)ct*MROWS + row];
    reds[tid] = s;
    __syncthreads();
    if (q == 0){
        s = reds[rloc] + reds[64+rloc] + reds[128+rloc] + reds[192+rloc];
        int tgt = caps[(row >> 6)*(TT+1) + (row & 63) + 1];
        reds[rloc] = (tgt != 0) ? (__logf(s) - t0arr[row]) : 0.f;
    }
    __syncthreads();
    if (tid < 32) reds[tid] += reds[tid+32];
    __syncthreads();
    if (tid < 16) reds[tid] += reds[tid+16];
    __syncthreads();
    if (tid < 8)  reds[tid] += reds[tid+8];
    __syncthreads();
    if (tid < 4)  reds[tid] += reds[tid+4];
    __syncthreads();
    if (tid == 0) bsum[blockIdx.x] = reds[0] + reds[1] + reds[2] + reds[3];
}

// ---------- loss stage 2: final sum / N (256 partials) ----------
__global__ __launch_bounds__(64) void k_loss2(const float* __restrict__ bsum, float* __restrict__ out){
    __shared__ float red[64];
    int tid = threadIdx.x;
    red[tid] = bsum[tid] + bsum[tid+64] + bsum[tid+128] + bsum[tid+192];
    __syncthreads();
    for (int off = 32; off > 0; off >>= 1){
        if (tid < off) red[tid] += red[tid+off];
        __syncthreads();
    }
    if (tid == 0) out[0] = red[0] / (float)NB;
}

extern "C" void kernel_launch(void* const* d_in, const int* in_sizes, int n_in,
                              void* d_out, int out_size, void* d_ws, size_t ws_size,
                              hipStream_t stream) {
    const float* features = (const float*)d_in[0];
    const int*   captions = (const int*)  d_in[1];
    const float* W_proj   = (const float*)d_in[2];
    const float* b_proj   = (const float*)d_in[3];
    const float* W_embed  = (const float*)d_in[4];
    const float* Wx       = (const float*)d_in[5];
    const float* Wh       = (const float*)d_in[6];
    const float* b_       = (const float*)d_in[7];
    const float* W_out    = (const float*)d_in[8];
    const float* b_out    = (const float*)d_in[9];
    float* out = (float*)d_out;

    char* ws = (char*)d_ws;
    // byte offsets (256-aligned)
    unsigned short* E2b   = (unsigned short*)(ws + 0);           // 10000*512*2 = 10,240,000
    float*          h0    = (float*)         (ws + 10240000);    // 256*512*4   =    524,288
    unsigned char*  WhT4  = (unsigned char*) (ws + 10764288);    // 512*256     =    131,072
    unsigned short* WxT   = (unsigned short*)(ws + 10895360);    // 512*256*2   =    262,144
    unsigned char*  WoT8p = (unsigned char*) (ws + 11157504);    // 79*4*16384  =  5,177,344
    float*          bop   = (float*)         (ws + 16334848);    // 10112*4     =     40,448
    unsigned char*  hA8   = (unsigned char*) (ws + 16375296);    // 128*4*16384 =  8,388,608
    float*          pps   = (float*)         (ws + 24763904);    // 79*16384*4  =  5,177,344
    float*          t0arr = (float*)         (ws + 29941248);    // 16384*4     =     65,536
    float*          bsum  = (float*)         (ws + 30006784);    // 256*4       =      1,024
    if (ws_size < 30007808u) return;

    k_prep<<<5992, 256, 0, stream>>>(features, W_proj, b_proj, h0,
                                     Wx, WxT, Wh, WhT4, W_out, WoT8p, b_out, bop);
    k_e2<<<dim3(157,4), 256, 0, stream>>>(W_embed, WxT, b_, E2b);
    k_rnn<<<NB, 512, 0, stream>>>(h0, WhT4, E2b, captions, hA8);
    k_scores<<<128*NCT, 512, 0, stream>>>(hA8, WoT8p, bop, pps);
    k_tsc<<<MROWS/4, 256, 0, stream>>>(hA8, WoT8p, b_out, captions, t0arr);
    k_loss1<<<256, 256, 0, stream>>>(pps, t0arr, captions, bsum);
    k_loss2<<<1, 64, 0, stream>>>(bsum, out);
}

// Round 22
// 294.688 us; speedup vs baseline: 1.1731x; 1.1731x over previous
//
#include <hip/hip_runtime.h>
#include <hip/hip_bf16.h>
#include <hip/hip_fp8.h>

// Problem constants
#define NB 256
#define TT 64
#define DD 1280
#define WW 256
#define HH 512
#define VV 10000
#define VP 10112           // vocab padded to 79*128
#define NCT 79             // number of 128-col vocab tiles
#define MROWS (NB*TT)      // 16384 score rows

typedef short short8 __attribute__((ext_vector_type(8)));
typedef float f32x4 __attribute__((ext_vector_type(4)));
typedef int   int4v __attribute__((ext_vector_type(4)));
typedef int   int8v __attribute__((ext_vector_type(8)));

static __device__ __forceinline__ unsigned short f2bf(float x){
    unsigned int u = __float_as_uint(x);
    unsigned int r = u + 0x7FFFu + ((u >> 16) & 1u);   // RNE
    return (unsigned short)(r >> 16);
}
static __device__ __forceinline__ float bf2f(unsigned short u){
    return __uint_as_float(((unsigned int)u) << 16);
}
static __device__ __forceinline__ unsigned char f2f8(float x){
    __hip_fp8_e4m3 q(x);                                // OCP e4m3fn
    return (unsigned char)q.__x;
}
static __device__ __forceinline__ float f82f(unsigned char b){
    __hip_fp8_e4m3 q; q.__x = b;
    return (float)q;
}
// fp4 e2m1 encode of x (round to nearest on the grid {0,.5,1,1.5,2,3,4,6})
static __device__ __forceinline__ unsigned enc4(float x){
    unsigned s = (x < 0.f) ? 8u : 0u;
    float a = fabsf(x);
    unsigned m;
    if      (a < 0.25f) m = 0;
    else if (a < 0.75f) m = 1;
    else if (a < 1.25f) m = 2;
    else if (a < 1.75f) m = 3;
    else if (a < 2.5f)  m = 4;
    else if (a < 3.5f)  m = 5;
    else if (a < 5.0f)  m = 6;
    else                m = 7;
    return s | m;
}
static __device__ __forceinline__ void gload16b(const unsigned char* g, unsigned char* l){
    __builtin_amdgcn_global_load_lds(
        (const __attribute__((address_space(1))) void*)g,
        (__attribute__((address_space(3))) void*)l, 16, 0, 0);
}

// K-tiled fp8 operand layout for the scores GEMM:
//   addr(row, k) = ((row>>7)*4 + (k>>7))*16384 + (row&127)*128 + (k&127)

// ---------- FUSED PREP: h0 | transpose_bf(Wx) | wh4 | transpose_f8(W_out) | biaspad ----------
// Sections by blockIdx.x: [0,256) h0 | [256,384) tbf | [384,896) wh4
//                         [896,5952) tf8 | [5952,5992) biaspad
__global__ __launch_bounds__(256) void k_prep(const float* __restrict__ feat,
                                              const float* __restrict__ W_proj,
                                              const float* __restrict__ bp,
                                              float* __restrict__ h0,
                                              const float* __restrict__ Wx,
                                              unsigned short* __restrict__ WxT,
                                              const float* __restrict__ Wh,
                                              unsigned char* __restrict__ WhT4,
                                              const float* __restrict__ W_out,
                                              unsigned char* __restrict__ WoT8p,
                                              const float* __restrict__ bo,
                                              float* __restrict__ bop){
    __shared__ unsigned short tileS[64][17];            // 2176 B
    __shared__ float fs[DD];                            // 5120 B (h0 section)
    int b = blockIdx.x;
    int tid = threadIdx.x;
    if (b < 256){
        // --- h0: one sample per block; thread covers cols tid and tid+256 (f32) ---
        int n = b;
        for (int i = tid; i < DD; i += 256) fs[i] = feat[(size_t)n*DD + i];
        __syncthreads();
        int c0 = tid, c1 = tid + 256;
        float a0 = 0.f, a1 = 0.f;
        for (int d = 0; d < DD; ++d){
            float fv = fs[d];
            a0 += fv * W_proj[(size_t)d*HH + c0];
            a1 += fv * W_proj[(size_t)d*HH + c1];
        }
        h0[(size_t)n*HH + c0] = a0 + bp[c0];
        h0[(size_t)n*HH + c1] = a1 + bp[c1];
    } else if (b < 384){
        // --- transpose_bf: Wx[256][512] -> WxT[512][256] bf16 ---
        int r = b - 256;                                // 8 x 16
        int c0 = (r & 7)*64, r0 = (r >> 3)*16;
        int c = tid & 63, rr = tid >> 6;
        #pragma unroll
        for (int j = 0; j < 4; ++j){
            int rw_ = rr + j*4;
            tileS[c][rw_] = f2bf(Wx[(size_t)(r0+rw_)*HH + c0 + c]);
        }
        __syncthreads();
        int rw = tid & 15, cw = tid >> 4;
        #pragma unroll
        for (int j = 0; j < 4; ++j){
            int c2 = cw + j*16;
            WxT[(size_t)(c0+c2)*WW + r0 + rw] = tileS[c2][rw];
        }
    } else if (b < 896){
        // --- wh4 ---
        int r = b - 384;                                // 512 blocks
        int j = r >> 1;                                 // k-pair 0..255
        int col = (r & 1)*256 + tid;
        float w0 = Wh[(size_t)(2*j  )*HH + col] * 32.0f;
        float w1 = Wh[(size_t)(2*j+1)*HH + col] * 32.0f;
        WhT4[(size_t)col*256 + j] = (unsigned char)(enc4(w0) | (enc4(w1) << 4));
    } else if (b < 5952){
        // --- transpose_f8: W_out[512][10000] -> K-tiled fp8 (pad cols to VP) ---
        unsigned char (*tileC)[20] = reinterpret_cast<unsigned char (*)[20]>(&tileS[0][0]);
        int r = b - 896;                                // 158 x 32
        int c0 = (r % 158)*64, r0 = (r / 158)*16;
        int c = tid & 63, rr = tid >> 6;
        #pragma unroll
        for (int j = 0; j < 4; ++j){
            int rw_ = rr + j*4;
            unsigned char v = 0;
            if (c0 + c < VV) v = f2f8(W_out[(size_t)(r0+rw_)*VV + c0 + c]);
            tileC[c][rw_] = v;
        }
        __syncthreads();
        int rw = tid & 15, cw = tid >> 4;
        #pragma unroll
        for (int j = 0; j < 4; ++j){
            int c2 = cw + j*16;
            int col = c0 + c2, k = r0 + rw;
            if (col < VP){
                size_t addr = ((size_t)((col >> 7)*4 + (k >> 7)))*16384
                            + (unsigned)((col & 127)*128 + (k & 127));
                WoT8p[addr] = tileC[c2][rw];
            }
        }
    } else {
        int i = (b - 5952)*256 + tid;
        // bias pre-scaled by log2(e) so the GEMM epilogue is one fma + one exp2
        if (i < VP) bop[i] = (i < VV) ? bo[i]*1.44269504f : -30000.0f;
    }
}

// ---------- E2[v][h] = sum_w W_embed[v][w] * Wx[w][h] + b[h]  (bf16 MFMA, bf16 out) ----------
// grid (157, 4): 8 cts per block for 4x latency-hiding parallelism.
__global__ __launch_bounds__(256) void k_e2(const float* __restrict__ We,
                                            const unsigned short* __restrict__ WxT,
                                            const float* __restrict__ bias,
                                            unsigned short* __restrict__ E2b){
    int lane = threadIdx.x & 63;
    int wv   = threadIdx.x >> 6;           // 0..3
    int l15 = lane & 15, lhi = lane >> 4;
    int rbase = blockIdx.x*64 + wv*16;
    int arow = rbase + l15; if (arow > VV-1) arow = VV-1;
    short8 a[8];
    #pragma unroll
    for (int kk = 0; kk < 8; ++kk){
        const float* src = We + (size_t)arow*WW + kk*32 + lhi*8;
        float4 g0 = *reinterpret_cast<const float4*>(src);
        float4 g1 = *reinterpret_cast<const float4*>(src + 4);
        short8 v;
        v[0]=(short)f2bf(g0.x); v[1]=(short)f2bf(g0.y); v[2]=(short)f2bf(g0.z); v[3]=(short)f2bf(g0.w);
        v[4]=(short)f2bf(g1.x); v[5]=(short)f2bf(g1.y); v[6]=(short)f2bf(g1.z); v[7]=(short)f2bf(g1.w);
        a[kk] = v;
    }
    int ct0 = blockIdx.y*8;
    for (int ct = ct0; ct < ct0+8; ++ct){
        int c0 = ct*16;
        f32x4 acc = {0.f,0.f,0.f,0.f};
        #pragma unroll
        for (int kk = 0; kk < 8; ++kk){
            short8 b = *reinterpret_cast<const short8*>(WxT + (size_t)(c0 + l15)*WW + kk*32 + lhi*8);
            acc = __builtin_amdgcn_mfma_f32_16x16x32_bf16(a[kk], b, acc, 0, 0, 0);
        }
        float bb = bias[c0 + l15];
        #pragma unroll
        for (int r = 0; r < 4; ++r){
            int row = rbase + lhi*4 + r;
            if (row < VV) E2b[(size_t)row*HH + c0 + l15] = f2bf(acc[r] + bb);
        }
    }
}

// ---------- RNN v4: 1 sample/block (256 blocks = 1/CU), 8 waves x 64 cols.
//             16 independent single-MFMA accumulators per step. ----------
__global__ __launch_bounds__(512) void k_rnn(const float* __restrict__ h0,
                                             const unsigned char* __restrict__ WhT4,
                                             const unsigned short* __restrict__ E2b,
                                             const int* __restrict__ caps,
                                             unsigned char* __restrict__ hA8){
    __shared__ __align__(32) unsigned char hl[2][HH];   // fp8 h, double-buffered (1 KB)
    int tid = threadIdx.x;
    int lane = tid & 63, wv = tid >> 6;      // 8 waves
    int l15 = lane & 15, lhi = lane >> 4;
    int n = blockIdx.x;
    int c0w = wv*64;                         // 64 cols per wave
    int mycol = c0w + lane;                  // col this lane finishes (ct==lhi)
    unsigned char* hbase = hA8 + ((size_t)((n>>1)*4 + (wv>>1)))*16384
                               + (unsigned)((n&1)*64*128 + (mycol & 127));

    int4v b[4][4];
    #pragma unroll
    for (int ct = 0; ct < 4; ++ct){
        int col = c0w + ct*16 + l15;
        #pragma unroll
        for (int kt = 0; kt < 4; ++kt){
            b[ct][kt] = *reinterpret_cast<const int4v*>(WhT4 + (size_t)col*256 + kt*64 + lhi*16);
            asm volatile("" : "+v"(b[ct][kt]));   // opaque: no remat / re-stream
        }
    }
    hl[0][tid] = f2f8(h0[(size_t)n*HH + tid]);
    __syncthreads();
    int cur = 0;
    const f32x4 z = {0.f,0.f,0.f,0.f};
    for (int t = 0; t < TT; ++t){
        int tok = caps[n*(TT+1) + t];
        unsigned short xv = E2b[(size_t)tok*HH + mycol];
        int8v a[4];
        #pragma unroll
        for (int kt = 0; kt < 4; ++kt)
            a[kt] = *reinterpret_cast<const int8v*>(&hl[cur][kt*128 + lhi*32]);
        f32x4 acc[4][4];
        #pragma unroll
        for (int ct = 0; ct < 4; ++ct)
            #pragma unroll
            for (int kt = 0; kt < 4; ++kt){
                int8v bb = __builtin_shufflevector(b[ct][kt], b[ct][kt], 0,1,2,3,0,1,2,3);
                acc[ct][kt] = __builtin_amdgcn_mfma_scale_f32_16x16x128_f8f6f4(
                    a[kt], bb, z,
                    0, 4,                        // cbsz=fp8(A), blgp=fp4(B)
                    0, (int)0x7F7F7F7F,          // A scale 2^0
                    0, (int)0x7A7A7A7A);         // B scale 2^-5
            }
        float s0 = (acc[0][0][0] + acc[0][1][0]) + (acc[0][2][0] + acc[0][3][0]);
        float s1 = (acc[1][0][0] + acc[1][1][0]) + (acc[1][2][0] + acc[1][3][0]);
        float s2 = (acc[2][0][0] + acc[2][1][0]) + (acc[2][2][0] + acc[2][3][0]);
        float s3 = (acc[3][0][0] + acc[3][1][0]) + (acc[3][2][0] + acc[3][3][0]);
        float v = (lhi == 0) ? s0 : (lhi == 1) ? s1 : (lhi == 2) ? s2 : s3;
        float x = v + bf2f(xv);
        float e = __expf(2.f*x);
        float th = 1.f - 2.f/(e + 1.f);          // tanh(x), saturates correctly
        unsigned char hv = f2f8(th);
        hl[cur^1][mycol] = hv;
        hbase[t*128] = hv;                       // K-tiled store, coalesced per wave
        __syncthreads();
        cur ^= 1;
    }
}

// ---------- scores: MX-fp8 GEMM, round-20 form (measured best: 147.5 us) ----------
__global__ __launch_bounds__(512) void k_scores(const unsigned char* __restrict__ hA8,
                                                const unsigned char* __restrict__ WoT8p,
                                                const float* __restrict__ bop,
                                                float* __restrict__ pps){  // [NCT][MROWS]
    __shared__ unsigned char As[16384];   // 16 KB
    __shared__ unsigned char Bs[16384];   // 16 KB
    int bid = blockIdx.x;
    int x = bid & 7;                 // XCD (blocks round-robin across XCDs)
    int local = bid >> 3;            // 0..1263
    int ct = local >> 4;             // ct-major within XCD
    int rt = x*16 + (local & 15);    // rt-minor: 16 consecutive row-tiles per XCD

    int tid = threadIdx.x;
    int lane = tid & 63, wv = tid >> 6;      // 8 waves
    int l15 = lane & 15, lhi = lane >> 4;
    int wr = wv >> 1, wc = wv & 1;           // 4 x 2 wave grid: 32 rows x 64 cols each
    const unsigned char* Abase = hA8   + (size_t)rt*65536;   // panel rt, 4 kt blocks
    const unsigned char* Bbase = WoT8p + (size_t)ct*65536;   // panel ct, 4 kt blocks

    unsigned coff[2];
    #pragma unroll
    for (int i = 0; i < 2; ++i){
        unsigned chunk = (unsigned)(i*512 + tid);
        unsigned rowloc = chunk >> 3;
        coff[i] = rowloc*128 + (((chunk & 7u) ^ (rowloc & 7u))*16u);
    }

    f32x4 acc[2][4];
    #pragma unroll
    for (int m = 0; m < 2; ++m)
        #pragma unroll
        for (int n = 0; n < 4; ++n)
            acc[m][n] = (f32x4){0.f,0.f,0.f,0.f};

    for (int kt = 0; kt < 4; ++kt){
        #pragma unroll
        for (int i = 0; i < 2; ++i){
            gload16b(Abase + kt*16384 + coff[i], As + (unsigned)((i*512 + tid) * 16));
            gload16b(Bbase + kt*16384 + coff[i], Bs + (unsigned)((i*512 + tid) * 16));
        }
        __syncthreads();
        int8v af[2];
        #pragma unroll
        for (int m = 0; m < 2; ++m){
            unsigned row = (unsigned)(wr*32 + m*16 + l15);
            int4v c0 = *reinterpret_cast<const int4v*>(As + row*128 + (((unsigned)(lhi*2+0) ^ (row&7))*16));
            int4v c1 = *reinterpret_cast<const int4v*>(As + row*128 + (((unsigned)(lhi*2+1) ^ (row&7))*16));
            af[m] = __builtin_shufflevector(c0, c1, 0,1,2,3,4,5,6,7);
        }
        #pragma unroll
        for (int n = 0; n < 4; ++n){
            unsigned col = (unsigned)(wc*64 + n*16 + l15);
            int4v c0 = *reinterpret_cast<const int4v*>(Bs + col*128 + (((unsigned)(lhi*2+0) ^ (col&7))*16));
            int4v c1 = *reinterpret_cast<const int4v*>(Bs + col*128 + (((unsigned)(lhi*2+1) ^ (col&7))*16));
            int8v bf = __builtin_shufflevector(c0, c1, 0,1,2,3,4,5,6,7);
            #pragma unroll
            for (int m = 0; m < 2; ++m)
                acc[m][n] = __builtin_amdgcn_mfma_scale_f32_16x16x128_f8f6f4(
                    af[m], bf, acc[m][n],
                    0, 0,
                    0, (int)0x7F7F7F7F,
                    0, (int)0x7F7F7F7F);
        }
        __syncthreads();
    }

    const float LOG2E = 1.44269504f;
    float srun[2][4];
    #pragma unroll
    for (int m = 0; m < 2; ++m)
        #pragma unroll
        for (int r = 0; r < 4; ++r) srun[m][r] = 0.f;
    #pragma unroll
    for (int n = 0; n < 4; ++n){
        int colg = ct*128 + wc*64 + n*16 + l15;
        float bb2 = bop[colg];                         // already * log2e (or -30000)
        #pragma unroll
        for (int m = 0; m < 2; ++m)
            #pragma unroll
            for (int r = 0; r < 4; ++r)
                srun[m][r] += exp2f(fmaf(acc[m][n][r], LOG2E, bb2));
    }
    #pragma unroll
    for (int off = 1; off < 16; off <<= 1)
        #pragma unroll
        for (int m = 0; m < 2; ++m)
            #pragma unroll
            for (int r = 0; r < 4; ++r)
                srun[m][r] += __shfl_xor(srun[m][r], off, 64);
    // cross-wc reduction: waves (wr,0) and (wr,1) hold partials for the SAME rows.
    float* red = (float*)As;   // 128 floats (loop-final barrier drained all As reads)
    if (wc == 1 && l15 == 0){
        #pragma unroll
        for (int m = 0; m < 2; ++m)
            #pragma unroll
            for (int r = 0; r < 4; ++r){
                int ri = wr*32 + m*16 + lhi*4 + r;      // 0..127
                red[ri] = srun[m][r];
            }
    }
    __syncthreads();
    if (wc == 0 && l15 == 0){
        #pragma unroll
        for (int m = 0; m < 2; ++m)
            #pragma unroll
            for (int r = 0; r < 4; ++r){
                int ri = wr*32 + m*16 + lhi*4 + r;
                int gr = rt*128 + ri;
                pps[(size_t)ct*MROWS + gr] = srun[m][r] + red[ri];
            }
    }
}

// ---------- t0[row] = h8[row,:] . Wo8[:, tgt] + b_out[tgt]  (one wave per row) ----------
__global__ __launch_bounds__(256) void k_tsc(const unsigned char* __restrict__ hA8,
                                             const unsigned char* __restrict__ WoT8p,
                                             const float* __restrict__ bo,
                                             const int* __restrict__ caps,
                                             float* __restrict__ t0arr){
    int lane = threadIdx.x & 63, w = threadIdx.x >> 6;   // 4 waves
    int row = blockIdx.x*4 + w;                          // 4096 blocks
    int tgt = caps[(row >> 6)*(TT+1) + (row & 63) + 1];
    int k0 = lane*8;
    int ktile = k0 >> 7, kin = k0 & 127;
    const unsigned char* hp = hA8   + ((size_t)((row >> 7)*4 + ktile))*16384
                                    + (unsigned)((row & 127)*128 + kin);
    const unsigned char* wp = WoT8p + ((size_t)((tgt >> 7)*4 + ktile))*16384
                                    + (unsigned)((tgt & 127)*128 + kin);
    float sum = 0.f;
    #pragma unroll
    for (int j = 0; j < 8; ++j)
        sum += f82f(hp[j]) * f82f(wp[j]);
    #pragma unroll
    for (int off = 1; off < 64; off <<= 1)
        sum += __shfl_xor(sum, off, 64);
    if (lane == 0) t0arr[row] = sum + bo[tgt];
}

// ---------- loss stage 1: per-row nll, 256 blocks x 64 rows, 4-way ct-split ----------
__global__ __launch_bounds__(256) void k_loss1(const float* __restrict__ pps,
                                               const float* __restrict__ t0arr,
                                               const int* __restrict__ caps,
                                               float* __restrict__ bsum){
    __shared__ float reds[256];
    int tid = threadIdx.x;
    int rloc = tid & 63, q = tid >> 6;      // q = 0..3: ct quarter
    int row = blockIdx.x*64 + rloc;
    int c0 = q*20, c1 = (q == 3) ? NCT : c0 + 20;
    float s = 0.f;
    for (int ct = c0; ct < c1; ++ct)
        s += pps[(size_t)ct*MROWS + row];
    reds[tid] = s;
    __syncthreads();
    if (q == 0){
        s = reds[rloc] + reds[64+rloc] + reds[128+rloc] + reds[192+rloc];
        int tgt = caps[(row >> 6)*(TT+1) + (row & 63) + 1];
        reds[rloc] = (tgt != 0) ? (__logf(s) - t0arr[row]) : 0.f;
    }
    __syncthreads();
    if (tid < 32) reds[tid] += reds[tid+32];
    __syncthreads();
    if (tid < 16) reds[tid] += reds[tid+16];
    __syncthreads();
    if (tid < 8)  reds[tid] += reds[tid+8];
    __syncthreads();
    if (tid < 4)  reds[tid] += reds[tid+4];
    __syncthreads();
    if (tid == 0) bsum[blockIdx.x] = reds[0] + reds[1] + reds[2] + reds[3];
}

// ---------- loss stage 2: final sum / N (256 partials) ----------
__global__ __launch_bounds__(64) void k_loss2(const float* __restrict__ bsum, float* __restrict__ out){
    __shared__ float red[64];
    int tid = threadIdx.x;
    red[tid] = bsum[tid] + bsum[tid+64] + bsum[tid+128] + bsum[tid+192];
    __syncthreads();
    for (int off = 32; off > 0; off >>= 1){
        if (tid < off) red[tid] += red[tid+off];
        __syncthreads();
    }
    if (tid == 0) out[0] = red[0] / (float)NB;
}

extern "C" void kernel_launch(void* const* d_in, const int* in_sizes, int n_in,
                              void* d_out, int out_size, void* d_ws, size_t ws_size,
                              hipStream_t stream) {
    const float* features = (const float*)d_in[0];
    const int*   captions = (const int*)  d_in[1];
    const float* W_proj   = (const float*)d_in[2];
    const float* b_proj   = (const float*)d_in[3];
    const float* W_embed  = (const float*)d_in[4];
    const float* Wx       = (const float*)d_in[5];
    const float* Wh       = (const float*)d_in[6];
    const float* b_       = (const float*)d_in[7];
    const float* W_out    = (const float*)d_in[8];
    const float* b_out    = (const float*)d_in[9];
    float* out = (float*)d_out;

    char* ws = (char*)d_ws;
    // byte offsets (256-aligned)
    unsigned short* E2b   = (unsigned short*)(ws + 0);           // 10000*512*2 = 10,240,000
    float*          h0    = (float*)         (ws + 10240000);    // 256*512*4   =    524,288
    unsigned char*  WhT4  = (unsigned char*) (ws + 10764288);    // 512*256     =    131,072
    unsigned short* WxT   = (unsigned short*)(ws + 10895360);    // 512*256*2   =    262,144
    unsigned char*  WoT8p = (unsigned char*) (ws + 11157504);    // 79*4*16384  =  5,177,344
    float*          bop   = (float*)         (ws + 16334848);    // 10112*4     =     40,448
    unsigned char*  hA8   = (unsigned char*) (ws + 16375296);    // 128*4*16384 =  8,388,608
    float*          pps   = (float*)         (ws + 24763904);    // 79*16384*4  =  5,177,344
    float*          t0arr = (float*)         (ws + 29941248);    // 16384*4     =     65,536
    float*          bsum  = (float*)         (ws + 30006784);    // 256*4       =      1,024
    if (ws_size < 30007808u) return;

    k_prep<<<5992, 256, 0, stream>>>(features, W_proj, b_proj, h0,
                                     Wx, WxT, Wh, WhT4, W_out, WoT8p, b_out, bop);
    k_e2<<<dim3(157,4), 256, 0, stream>>>(W_embed, WxT, b_, E2b);
    k_rnn<<<NB, 512, 0, stream>>>(h0, WhT4, E2b, captions, hA8);
    k_scores<<<128*NCT, 512, 0, stream>>>(hA8, WoT8p, bop, pps);
    k_tsc<<<MROWS/4, 256, 0, stream>>>(hA8, WoT8p, b_out, captions, t0arr);
    k_loss1<<<256, 256, 0, stream>>>(pps, t0arr, captions, bsum);
    k_loss2<<<1, 64, 0, stream>>>(bsum, out);
}

// Round 23
// 286.561 us; speedup vs baseline: 1.2064x; 1.0284x over previous
//
#include <hip/hip_runtime.h>
#include <hip/hip_bf16.h>
#include <hip/hip_fp8.h>

// Problem constants
#define NB 256
#define TT 64
#define DD 1280
#define WW 256
#define HH 512
#define VV 10000
#define VP 10112           // vocab padded to 79*128
#define NCT 79             // number of 128-col vocab tiles
#define MROWS (NB*TT)      // 16384 score rows

typedef short short8 __attribute__((ext_vector_type(8)));
typedef float f32x4 __attribute__((ext_vector_type(4)));
typedef int   int4v __attribute__((ext_vector_type(4)));
typedef int   int8v __attribute__((ext_vector_type(8)));

static __device__ __forceinline__ unsigned short f2bf(float x){
    unsigned int u = __float_as_uint(x);
    unsigned int r = u + 0x7FFFu + ((u >> 16) & 1u);   // RNE
    return (unsigned short)(r >> 16);
}
static __device__ __forceinline__ float bf2f(unsigned short u){
    return __uint_as_float(((unsigned int)u) << 16);
}
static __device__ __forceinline__ unsigned char f2f8(float x){
    __hip_fp8_e4m3 q(x);                                // OCP e4m3fn
    return (unsigned char)q.__x;
}
static __device__ __forceinline__ float f82f(unsigned char b){
    __hip_fp8_e4m3 q; q.__x = b;
    return (float)q;
}
// fp4 e2m1 encode of x (round to nearest on the grid {0,.5,1,1.5,2,3,4,6})
static __device__ __forceinline__ unsigned enc4(float x){
    unsigned s = (x < 0.f) ? 8u : 0u;
    float a = fabsf(x);
    unsigned m;
    if      (a < 0.25f) m = 0;
    else if (a < 0.75f) m = 1;
    else if (a < 1.25f) m = 2;
    else if (a < 1.75f) m = 3;
    else if (a < 2.5f)  m = 4;
    else if (a < 3.5f)  m = 5;
    else if (a < 5.0f)  m = 6;
    else                m = 7;
    return s | m;
}
static __device__ __forceinline__ void gload16b(const unsigned char* g, unsigned char* l){
    __builtin_amdgcn_global_load_lds(
        (const __attribute__((address_space(1))) void*)g,
        (__attribute__((address_space(3))) void*)l, 16, 0, 0);
}

// K-tiled fp8 operand layout for the scores GEMM:
//   addr(row, k) = ((row>>7)*4 + (k>>7))*16384 + (row&127)*128 + (k&127)

// ---------- FUSED PREP: h0 | transpose_bf(Wx) | wh4 | transpose_f8(W_out) | biaspad ----------
// Sections by blockIdx.x: [0,256) h0 | [256,384) tbf | [384,896) wh4
//                         [896,5952) tf8 | [5952,5992) biaspad
__global__ __launch_bounds__(256) void k_prep(const float* __restrict__ feat,
                                              const float* __restrict__ W_proj,
                                              const float* __restrict__ bp,
                                              float* __restrict__ h0,
                                              const float* __restrict__ Wx,
                                              unsigned short* __restrict__ WxT,
                                              const float* __restrict__ Wh,
                                              unsigned char* __restrict__ WhT4,
                                              const float* __restrict__ W_out,
                                              unsigned char* __restrict__ WoT8p,
                                              const float* __restrict__ bo,
                                              float* __restrict__ bop){
    __shared__ unsigned short tileS[64][17];            // 2176 B
    __shared__ float fs[DD];                            // 5120 B (h0 section)
    int b = blockIdx.x;
    int tid = threadIdx.x;
    if (b < 256){
        // --- h0: one sample per block; thread covers cols tid and tid+256 (f32) ---
        int n = b;
        for (int i = tid; i < DD; i += 256) fs[i] = feat[(size_t)n*DD + i];
        __syncthreads();
        int c0 = tid, c1 = tid + 256;
        float a0 = 0.f, a1 = 0.f;
        for (int d = 0; d < DD; ++d){
            float fv = fs[d];
            a0 += fv * W_proj[(size_t)d*HH + c0];
            a1 += fv * W_proj[(size_t)d*HH + c1];
        }
        h0[(size_t)n*HH + c0] = a0 + bp[c0];
        h0[(size_t)n*HH + c1] = a1 + bp[c1];
    } else if (b < 384){
        // --- transpose_bf: Wx[256][512] -> WxT[512][256] bf16 ---
        int r = b - 256;                                // 8 x 16
        int c0 = (r & 7)*64, r0 = (r >> 3)*16;
        int c = tid & 63, rr = tid >> 6;
        #pragma unroll
        for (int j = 0; j < 4; ++j){
            int rw_ = rr + j*4;
            tileS[c][rw_] = f2bf(Wx[(size_t)(r0+rw_)*HH + c0 + c]);
        }
        __syncthreads();
        int rw = tid & 15, cw = tid >> 4;
        #pragma unroll
        for (int j = 0; j < 4; ++j){
            int c2 = cw + j*16;
            WxT[(size_t)(c0+c2)*WW + r0 + rw] = tileS[c2][rw];
        }
    } else if (b < 896){
        // --- wh4 ---
        int r = b - 384;                                // 512 blocks
        int j = r >> 1;                                 // k-pair 0..255
        int col = (r & 1)*256 + tid;
        float w0 = Wh[(size_t)(2*j  )*HH + col] * 32.0f;
        float w1 = Wh[(size_t)(2*j+1)*HH + col] * 32.0f;
        WhT4[(size_t)col*256 + j] = (unsigned char)(enc4(w0) | (enc4(w1) << 4));
    } else if (b < 5952){
        // --- transpose_f8: W_out[512][10000] -> K-tiled fp8 (pad cols to VP) ---
        // Store side vectorized: 16 consecutive k-bytes of a column are contiguous
        // in the K-tiled layout -> 64 threads x one 16B store (vs 1024 byte stores).
        unsigned char (*tileC)[20] = reinterpret_cast<unsigned char (*)[20]>(&tileS[0][0]);
        int r = b - 896;                                // 158 x 32
        int c0 = (r % 158)*64, r0 = (r / 158)*16;
        int c = tid & 63, rr = tid >> 6;
        #pragma unroll
        for (int j = 0; j < 4; ++j){
            int rw_ = rr + j*4;
            unsigned char v = 0;
            if (c0 + c < VV) v = f2f8(W_out[(size_t)(r0+rw_)*VV + c0 + c]);
            tileC[c][rw_] = v;
        }
        __syncthreads();
        if (tid < 64){
            int col = c0 + tid;
            if (col < VP){
                const unsigned* src = reinterpret_cast<const unsigned*>(&tileC[tid][0]);
                uint4 v = make_uint4(src[0], src[1], src[2], src[3]);   // k r0..r0+15
                size_t addr = ((size_t)((col >> 7)*4 + (r0 >> 7)))*16384
                            + (unsigned)((col & 127)*128 + (r0 & 127));
                *reinterpret_cast<uint4*>(WoT8p + addr) = v;
            }
        }
    } else {
        int i = (b - 5952)*256 + tid;
        // bias pre-scaled by log2(e) so the GEMM epilogue is one fma + one exp2
        if (i < VP) bop[i] = (i < VV) ? bo[i]*1.44269504f : -30000.0f;
    }
}

// ---------- E2[v][h] = sum_w W_embed[v][w] * Wx[w][h] + b[h]  (bf16 MFMA, bf16 out) ----------
// grid (157, 4): 8 cts per block for 4x latency-hiding parallelism.
__global__ __launch_bounds__(256) void k_e2(const float* __restrict__ We,
                                            const unsigned short* __restrict__ WxT,
                                            const float* __restrict__ bias,
                                            unsigned short* __restrict__ E2b){
    int lane = threadIdx.x & 63;
    int wv   = threadIdx.x >> 6;           // 0..3
    int l15 = lane & 15, lhi = lane >> 4;
    int rbase = blockIdx.x*64 + wv*16;
    int arow = rbase + l15; if (arow > VV-1) arow = VV-1;
    short8 a[8];
    #pragma unroll
    for (int kk = 0; kk < 8; ++kk){
        const float* src = We + (size_t)arow*WW + kk*32 + lhi*8;
        float4 g0 = *reinterpret_cast<const float4*>(src);
        float4 g1 = *reinterpret_cast<const float4*>(src + 4);
        short8 v;
        v[0]=(short)f2bf(g0.x); v[1]=(short)f2bf(g0.y); v[2]=(short)f2bf(g0.z); v[3]=(short)f2bf(g0.w);
        v[4]=(short)f2bf(g1.x); v[5]=(short)f2bf(g1.y); v[6]=(short)f2bf(g1.z); v[7]=(short)f2bf(g1.w);
        a[kk] = v;
    }
    int ct0 = blockIdx.y*8;
    for (int ct = ct0; ct < ct0+8; ++ct){
        int c0 = ct*16;
        f32x4 acc = {0.f,0.f,0.f,0.f};
        #pragma unroll
        for (int kk = 0; kk < 8; ++kk){
            short8 b = *reinterpret_cast<const short8*>(WxT + (size_t)(c0 + l15)*WW + kk*32 + lhi*8);
            acc = __builtin_amdgcn_mfma_f32_16x16x32_bf16(a[kk], b, acc, 0, 0, 0);
        }
        float bb = bias[c0 + l15];
        #pragma unroll
        for (int r = 0; r < 4; ++r){
            int row = rbase + lhi*4 + r;
            if (row < VV) E2b[(size_t)row*HH + c0 + l15] = f2bf(acc[r] + bb);
        }
    }
}

// ---------- RNN v5: 1 sample/block, 8 waves x 64 cols; 16 independent MFMAs/step;
//             xWxb gather PREFETCHED one step ahead (tok[t+1] known at step t) so
//             the L3-class E2b latency (~450cy) hides under a full step (~3000cy).
__global__ __launch_bounds__(512) void k_rnn(const float* __restrict__ h0,
                                             const unsigned char* __restrict__ WhT4,
                                             const unsigned short* __restrict__ E2b,
                                             const int* __restrict__ caps,
                                             unsigned char* __restrict__ hA8){
    __shared__ __align__(32) unsigned char hl[2][HH];   // fp8 h, double-buffered (1 KB)
    int tid = threadIdx.x;
    int lane = tid & 63, wv = tid >> 6;      // 8 waves
    int l15 = lane & 15, lhi = lane >> 4;
    int n = blockIdx.x;
    int c0w = wv*64;                         // 64 cols per wave
    int mycol = c0w + lane;                  // col this lane finishes (ct==lhi)
    unsigned char* hbase = hA8 + ((size_t)((n>>1)*4 + (wv>>1)))*16384
                               + (unsigned)((n&1)*64*128 + (mycol & 127));

    int4v b[4][4];
    #pragma unroll
    for (int ct = 0; ct < 4; ++ct){
        int col = c0w + ct*16 + l15;
        #pragma unroll
        for (int kt = 0; kt < 4; ++kt){
            b[ct][kt] = *reinterpret_cast<const int4v*>(WhT4 + (size_t)col*256 + kt*64 + lhi*16);
            asm volatile("" : "+v"(b[ct][kt]));   // opaque: no remat / re-stream
        }
    }
    hl[0][tid] = f2f8(h0[(size_t)n*HH + tid]);
    // prefetch xWxb for t=0
    unsigned short xv = E2b[(size_t)caps[n*(TT+1)]*HH + mycol];
    __syncthreads();
    int cur = 0;
    const f32x4 z = {0.f,0.f,0.f,0.f};
    for (int t = 0; t < TT; ++t){
        // issue next step's gather now (consumed at t+1 -> full-step latency cover)
        unsigned short xv_next = 0;
        if (t + 1 < TT)
            xv_next = E2b[(size_t)caps[n*(TT+1) + t + 1]*HH + mycol];
        int8v a[4];
        #pragma unroll
        for (int kt = 0; kt < 4; ++kt)
            a[kt] = *reinterpret_cast<const int8v*>(&hl[cur][kt*128 + lhi*32]);
        f32x4 acc[4][4];
        #pragma unroll
        for (int ct = 0; ct < 4; ++ct)
            #pragma unroll
            for (int kt = 0; kt < 4; ++kt){
                int8v bb = __builtin_shufflevector(b[ct][kt], b[ct][kt], 0,1,2,3,0,1,2,3);
                acc[ct][kt] = __builtin_amdgcn_mfma_scale_f32_16x16x128_f8f6f4(
                    a[kt], bb, z,
                    0, 4,                        // cbsz=fp8(A), blgp=fp4(B)
                    0, (int)0x7F7F7F7F,          // A scale 2^0
                    0, (int)0x7A7A7A7A);         // B scale 2^-5
            }
        float s0 = (acc[0][0][0] + acc[0][1][0]) + (acc[0][2][0] + acc[0][3][0]);
        float s1 = (acc[1][0][0] + acc[1][1][0]) + (acc[1][2][0] + acc[1][3][0]);
        float s2 = (acc[2][0][0] + acc[2][1][0]) + (acc[2][2][0] + acc[2][3][0]);
        float s3 = (acc[3][0][0] + acc[3][1][0]) + (acc[3][2][0] + acc[3][3][0]);
        float v = (lhi == 0) ? s0 : (lhi == 1) ? s1 : (lhi == 2) ? s2 : s3;
        float x = v + bf2f(xv);
        float e = __expf(2.f*x);
        float th = 1.f - 2.f/(e + 1.f);          // tanh(x), saturates correctly
        unsigned char hv = f2f8(th);
        hl[cur^1][mycol] = hv;
        hbase[t*128] = hv;                       // K-tiled store, coalesced per wave
        xv = xv_next;
        __syncthreads();
        cur ^= 1;
    }
}

// ---------- scores: MX-fp8 GEMM (round-20 form) + appended tsc blocks ----------
// bid <  128*NCT : GEMM tile (unchanged, measured-best schedule)
// bid >= 128*NCT : t0[row] = h8[row,:].Wo8[:,tgt] + b_out[tgt], 8 rows/block
__global__ __launch_bounds__(512) void k_scores(const unsigned char* __restrict__ hA8,
                                                const unsigned char* __restrict__ WoT8p,
                                                const float* __restrict__ bop,
                                                const float* __restrict__ bo,
                                                const int* __restrict__ caps,
                                                float* __restrict__ t0arr,
                                                float* __restrict__ pps){  // [NCT][MROWS]
    __shared__ unsigned char As[16384];   // 16 KB
    __shared__ unsigned char Bs[16384];   // 16 KB
    int bid = blockIdx.x;
    int tid = threadIdx.x;
    int lane = tid & 63, wv = tid >> 6;      // 8 waves
    int l15 = lane & 15, lhi = lane >> 4;

    if (bid >= 128*NCT){
        // ---- tsc branch: one row per wave ----
        int row = (bid - 128*NCT)*8 + wv;
        int tgt = caps[(row >> 6)*(TT+1) + (row & 63) + 1];
        int k0 = lane*8;
        int ktile = k0 >> 7, kin = k0 & 127;
        const unsigned char* hp = hA8   + ((size_t)((row >> 7)*4 + ktile))*16384
                                        + (unsigned)((row & 127)*128 + kin);
        const unsigned char* wp = WoT8p + ((size_t)((tgt >> 7)*4 + ktile))*16384
                                        + (unsigned)((tgt & 127)*128 + kin);
        float sum = 0.f;
        #pragma unroll
        for (int j = 0; j < 8; ++j)
            sum += f82f(hp[j]) * f82f(wp[j]);
        #pragma unroll
        for (int off = 1; off < 64; off <<= 1)
            sum += __shfl_xor(sum, off, 64);
        if (lane == 0) t0arr[row] = sum + bo[tgt];
        return;
    }

    int x = bid & 7;                 // XCD (blocks round-robin across XCDs)
    int local = bid >> 3;            // 0..1263
    int ct = local >> 4;             // ct-major within XCD
    int rt = x*16 + (local & 15);    // rt-minor: 16 consecutive row-tiles per XCD
    int wr = wv >> 1, wc = wv & 1;   // 4 x 2 wave grid: 32 rows x 64 cols each
    const unsigned char* Abase = hA8   + (size_t)rt*65536;   // panel rt, 4 kt blocks
    const unsigned char* Bbase = WoT8p + (size_t)ct*65536;   // panel ct, 4 kt blocks

    unsigned coff[2];
    #pragma unroll
    for (int i = 0; i < 2; ++i){
        unsigned chunk = (unsigned)(i*512 + tid);
        unsigned rowloc = chunk >> 3;
        coff[i] = rowloc*128 + (((chunk & 7u) ^ (rowloc & 7u))*16u);
    }

    f32x4 acc[2][4];
    #pragma unroll
    for (int m = 0; m < 2; ++m)
        #pragma unroll
        for (int n = 0; n < 4; ++n)
            acc[m][n] = (f32x4){0.f,0.f,0.f,0.f};

    for (int kt = 0; kt < 4; ++kt){
        #pragma unroll
        for (int i = 0; i < 2; ++i){
            gload16b(Abase + kt*16384 + coff[i], As + (unsigned)((i*512 + tid) * 16));
            gload16b(Bbase + kt*16384 + coff[i], Bs + (unsigned)((i*512 + tid) * 16));
        }
        __syncthreads();
        int8v af[2];
        #pragma unroll
        for (int m = 0; m < 2; ++m){
            unsigned row = (unsigned)(wr*32 + m*16 + l15);
            int4v c0 = *reinterpret_cast<const int4v*>(As + row*128 + (((unsigned)(lhi*2+0) ^ (row&7))*16));
            int4v c1 = *reinterpret_cast<const int4v*>(As + row*128 + (((unsigned)(lhi*2+1) ^ (row&7))*16));
            af[m] = __builtin_shufflevector(c0, c1, 0,1,2,3,4,5,6,7);
        }
        #pragma unroll
        for (int n = 0; n < 4; ++n){
            unsigned col = (unsigned)(wc*64 + n*16 + l15);
            int4v c0 = *reinterpret_cast<const int4v*>(Bs + col*128 + (((unsigned)(lhi*2+0) ^ (col&7))*16));
            int4v c1 = *reinterpret_cast<const int4v*>(Bs + col*128 + (((unsigned)(lhi*2+1) ^ (col&7))*16));
            int8v bf = __builtin_shufflevector(c0, c1, 0,1,2,3,4,5,6,7);
            #pragma unroll
            for (int m = 0; m < 2; ++m)
                acc[m][n] = __builtin_amdgcn_mfma_scale_f32_16x16x128_f8f6f4(
                    af[m], bf, acc[m][n],
                    0, 0,
                    0, (int)0x7F7F7F7F,
                    0, (int)0x7F7F7F7F);
        }
        __syncthreads();
    }

    const float LOG2E = 1.44269504f;
    float srun[2][4];
    #pragma unroll
    for (int m = 0; m < 2; ++m)
        #pragma unroll
        for (int r = 0; r < 4; ++r) srun[m][r] = 0.f;
    #pragma unroll
    for (int n = 0; n < 4; ++n){
        int colg = ct*128 + wc*64 + n*16 + l15;
        float bb2 = bop[colg];                         // already * log2e (or -30000)
        #pragma unroll
        for (int m = 0; m < 2; ++m)
            #pragma unroll
            for (int r = 0; r < 4; ++r)
                srun[m][r] += exp2f(fmaf(acc[m][n][r], LOG2E, bb2));
    }
    #pragma unroll
    for (int off = 1; off < 16; off <<= 1)
        #pragma unroll
        for (int m = 0; m < 2; ++m)
            #pragma unroll
            for (int r = 0; r < 4; ++r)
                srun[m][r] += __shfl_xor(srun[m][r], off, 64);
    // cross-wc reduction: waves (wr,0) and (wr,1) hold partials for the SAME rows.
    float* red = (float*)As;   // 128 floats (loop-final barrier drained all As reads)
    if (wc == 1 && l15 == 0){
        #pragma unroll
        for (int m = 0; m < 2; ++m)
            #pragma unroll
            for (int r = 0; r < 4; ++r){
                int ri = wr*32 + m*16 + lhi*4 + r;      // 0..127
                red[ri] = srun[m][r];
            }
    }
    __syncthreads();
    if (wc == 0 && l15 == 0){
        #pragma unroll
        for (int m = 0; m < 2; ++m)
            #pragma unroll
            for (int r = 0; r < 4; ++r){
                int ri = wr*32 + m*16 + lhi*4 + r;
                int gr = rt*128 + ri;
                pps[(size_t)ct*MROWS + gr] = srun[m][r] + red[ri];
            }
    }
}

// ---------- loss stage 1: per-row nll, 256 blocks x 64 rows, 4-way ct-split ----------
__global__ __launch_bounds__(256) void k_loss1(const float* __restrict__ pps,
                                               const float* __restrict__ t0arr,
                                               const int* __restrict__ caps,
                                               float* __restrict__ bsum){
    __shared__ float reds[256];
    int tid = threadIdx.x;
    int rloc = tid & 63, q = tid >> 6;      // q = 0..3: ct quarter
    int row = blockIdx.x*64 + rloc;
    int c0 = q*20, c1 = (q == 3) ? NCT : c0 + 20;
    float s = 0.f;
    for (int ct = c0; ct < c1; ++ct)
        s += pps[(size_t)ct*MROWS + row];
    reds[tid] = s;
    __syncthreads();
    if (q == 0){
        s = reds[rloc] + reds[64+rloc] + reds[128+rloc] + reds[192+rloc];
        int tgt = caps[(row >> 6)*(TT+1) + (row & 63) + 1];
        reds[rloc] = (tgt != 0) ? (__logf(s) - t0arr[row]) : 0.f;
    }
    __syncthreads();
    if (tid < 32) reds[tid] += reds[tid+32];
    __syncthreads();
    if (tid < 16) reds[tid] += reds[tid+16];
    __syncthreads();
    if (tid < 8)  reds[tid] += reds[tid+8];
    __syncthreads();
    if (tid < 4)  reds[tid] += reds[tid+4];
    __syncthreads();
    if (tid == 0) bsum[blockIdx.x] = reds[0] + reds[1] + reds[2] + reds[3];
}

// ---------- loss stage 2: final sum / N (256 partials) ----------
__global__ __launch_bounds__(64) void k_loss2(const float* __restrict__ bsum, float* __restrict__ out){
    __shared__ float red[64];
    int tid = threadIdx.x;
    red[tid] = bsum[tid] + bsum[tid+64] + bsum[tid+128] + bsum[tid+192];
    __syncthreads();
    for (int off = 32; off > 0; off >>= 1){
        if (tid < off) red[tid] += red[tid+off];
        __syncthreads();
    }
    if (tid == 0) out[0] = red[0] / (float)NB;
}

extern "C" void kernel_launch(void* const* d_in, const int* in_sizes, int n_in,
                              void* d_out, int out_size, void* d_ws, size_t ws_size,
                              hipStream_t stream) {
    const float* features = (const float*)d_in[0];
    const int*   captions = (const int*)  d_in[1];
    const float* W_proj   = (const float*)d_in[2];
    const float* b_proj   = (const float*)d_in[3];
    const float* W_embed  = (const float*)d_in[4];
    const float* Wx       = (const float*)d_in[5];
    const float* Wh       = (const float*)d_in[6];
    const float* b_       = (const float*)d_in[7];
    const float* W_out    = (const float*)d_in[8];
    const float* b_out    = (const float*)d_in[9];
    float* out = (float*)d_out;

    char* ws = (char*)d_ws;
    // byte offsets (256-aligned)
    unsigned short* E2b   = (unsigned short*)(ws + 0);           // 10000*512*2 = 10,240,000
    float*          h0    = (float*)         (ws + 10240000);    // 256*512*4   =    524,288
    unsigned char*  WhT4  = (unsigned char*) (ws + 10764288);    // 512*256     =    131,072
    unsigned short* WxT   = (unsigned short*)(ws + 10895360);    // 512*256*2   =    262,144
    unsigned char*  WoT8p = (unsigned char*) (ws + 11157504);    // 79*4*16384  =  5,177,344
    float*          bop   = (float*)         (ws + 16334848);    // 10112*4     =     40,448
    unsigned char*  hA8   = (unsigned char*) (ws + 16375296);    // 128*4*16384 =  8,388,608
    float*          pps   = (float*)         (ws + 24763904);    // 79*16384*4  =  5,177,344
    float*          t0arr = (float*)         (ws + 29941248);    // 16384*4     =     65,536
    float*          bsum  = (float*)         (ws + 30006784);    // 256*4       =      1,024
    if (ws_size < 30007808u) return;

    k_prep<<<5992, 256, 0, stream>>>(features, W_proj, b_proj, h0,
                                     Wx, WxT, Wh, WhT4, W_out, WoT8p, b_out, bop);
    k_e2<<<dim3(157,4), 256, 0, stream>>>(W_embed, WxT, b_, E2b);
    k_rnn<<<NB, 512, 0, stream>>>(h0, WhT4, E2b, captions, hA8);
    k_scores<<<128*NCT + MROWS/8, 512, 0, stream>>>(hA8, WoT8p, bop, b_out, captions, t0arr, pps);
    k_loss1<<<256, 256, 0, stream>>>(pps, t0arr, captions, bsum);
    k_loss2<<<1, 64, 0, stream>>>(bsum, out);
}